// Round 7
// baseline (188.526 us; speedup 1.0000x reference)
//
#include <hip/hip_runtime.h>
#include <stdint.h>

typedef unsigned short ushort_t;
typedef __bf16 bf16x8 __attribute__((ext_vector_type(8)));
typedef float f32x4 __attribute__((ext_vector_type(4)));

#define M_TOK 8192
#define K1 1024
#define N1 4096
#define K2 4160   /* 4096 (h) + 16 (probs/b2) + 48 zero-pad */
#define N2 1024

template <int V> struct ic { static constexpr int value = V; };

__device__ __forceinline__ ushort_t f2bf(float f) {
  union { float f; unsigned u; } v; v.f = f;
  unsigned u = v.u;
  u += 0x7FFFu + ((u >> 16) & 1u);   // RNE; inputs finite
  return (ushort_t)(u >> 16);
}

__device__ __forceinline__ void gload16(const void* g, void* l) {
  __builtin_amdgcn_global_load_lds((__attribute__((address_space(1))) void*)g,
                                   (__attribute__((address_space(3))) void*)l,
                                   16, 0, 0);
}

// ---------------- merged prep: wprep (blocks 0..2303) + probs (2304..4351) --
__global__ __launch_bounds__(256) void k_prep(
    const float* __restrict__ x, const float* __restrict__ node_w,
    const float* __restrict__ node_b, const float* __restrict__ w1,
    const float* __restrict__ w2, const float* __restrict__ b2,
    ushort_t* __restrict__ xb, float* __restrict__ probs,
    ushort_t* __restrict__ w1t, ushort_t* __restrict__ w2t,
    ushort_t* __restrict__ hp) {
  __shared__ ushort_t tile[64][68];
  const int b = blockIdx.x;
  if (b < 1024) {
    // w1t[l*256+h][k] = w1[l][k][h]
    const int tr = threadIdx.x >> 4, tc = (threadIdx.x & 15) * 4;
    const int l = b >> 6, rem = b & 63;
    const int kt = rem >> 2, ht = rem & 3;
    const float* in = w1 + (size_t)l * K1 * 256;
#pragma unroll
    for (int rr = 0; rr < 4; ++rr) {
      int r = tr + rr * 16;
      float4 v = *(const float4*)(in + (size_t)(kt * 64 + r) * 256 + ht * 64 + tc);
      tile[r][tc+0] = f2bf(v.x); tile[r][tc+1] = f2bf(v.y);
      tile[r][tc+2] = f2bf(v.z); tile[r][tc+3] = f2bf(v.w);
    }
    __syncthreads();
#pragma unroll
    for (int rr = 0; rr < 4; ++rr) {
      int oh = tr + rr * 16;
      ushort4 o;
      o.x = tile[tc+0][oh]; o.y = tile[tc+1][oh];
      o.z = tile[tc+2][oh]; o.w = tile[tc+3][oh];
      *(ushort4*)(w1t + (size_t)(l * 256 + ht * 64 + oh) * K1 + kt * 64 + tc) = o;
    }
  } else if (b < 2048) {
    // w2t[d][l*256+h] = w2[l][h][d]
    const int tr = threadIdx.x >> 4, tc = (threadIdx.x & 15) * 4;
    const int bb = b - 1024;
    const int l = bb >> 6, rem = bb & 63;
    const int ht = rem >> 4, dt = rem & 15;
    const float* in = w2 + (size_t)l * 256 * N2;
#pragma unroll
    for (int rr = 0; rr < 4; ++rr) {
      int r = tr + rr * 16;
      float4 v = *(const float4*)(in + (size_t)(ht * 64 + r) * N2 + dt * 64 + tc);
      tile[r][tc+0] = f2bf(v.x); tile[r][tc+1] = f2bf(v.y);
      tile[r][tc+2] = f2bf(v.z); tile[r][tc+3] = f2bf(v.w);
    }
    __syncthreads();
#pragma unroll
    for (int rr = 0; rr < 4; ++rr) {
      int od = tr + rr * 16;
      ushort4 o;
      o.x = tile[tc+0][od]; o.y = tile[tc+1][od];
      o.z = tile[tc+2][od]; o.w = tile[tc+3][od];
      *(ushort4*)(w2t + (size_t)(dt * 64 + od) * K2 + l * 256 + ht * 64 + tc) = o;
    }
  } else if (b < 2304) {
    int tid = (b - 2048) * 256 + threadIdx.x;   // 1024 * 64
    int d = tid >> 6, cc = tid & 63;
    float v = (cc < 16) ? b2[cc * N2 + d] : 0.f;
    w2t[(size_t)d * K2 + 4096 + cc] = f2bf(v);
  } else {
    // probs + x->bf16; 1 wave per token
    const int wid = threadIdx.x >> 6, lane = threadIdx.x & 63;
    const int t = (b - 2304) * 4 + wid;
    const float* xr = x + (size_t)t * K1;
    float xv[16];
#pragma unroll
    for (int j = 0; j < 4; ++j) {
      float4 v = *(const float4*)(xr + j * 256 + lane * 4);
      xv[4*j+0] = v.x; xv[4*j+1] = v.y; xv[4*j+2] = v.z; xv[4*j+3] = v.w;
    }
    ushort_t* xbr = xb + (size_t)t * K1;
#pragma unroll
    for (int j = 0; j < 4; ++j) {
      ushort4 o;
      o.x = f2bf(xv[4*j+0]); o.y = f2bf(xv[4*j+1]);
      o.z = f2bf(xv[4*j+2]); o.w = f2bf(xv[4*j+3]);
      *(ushort4*)(xbr + j * 256 + lane * 4) = o;
    }
    float c[15];
#pragma unroll
    for (int n = 0; n < 15; ++n) {
      float s = 0.f;
      const float* wr = node_w + n * K1;
#pragma unroll
      for (int j = 0; j < 4; ++j) {
        float4 w = *(const float4*)(wr + j * 256 + lane * 4);
        s += xv[4*j+0]*w.x + xv[4*j+1]*w.y + xv[4*j+2]*w.z + xv[4*j+3]*w.w;
      }
#pragma unroll
      for (int off = 32; off > 0; off >>= 1) s += __shfl_xor(s, off);
      float z = s + node_b[n];
      c[n] = 1.f / (1.f + __expf(-z));
    }
    if (lane < 16) {
      float p = 1.f;
#pragma unroll
      for (int m = 0; m < 4; ++m) {
        int jm = lane >> (4 - m);
        int node = (1 << m) - 1 + jm;
        int bit = (lane >> (3 - m)) & 1;
        p *= bit ? (1.f - c[node]) : c[node];
      }
      probs[t * 16 + lane] = p;
      hp[(size_t)t * K2 + 4096 + lane] = f2bf(p);
    }
    if (lane < 48) hp[(size_t)t * K2 + 4112 + lane] = 0;
  }
}

// ---------------- BMxBN MFMA GEMM, BK=32, 2 regions/K-tile, 2 blocks/CU -----
// LDS: A [2 buf][BM][32] 64B rows; B [2 buf][2 half][BN/2][32]. Swizzle:
// 16B slot XOR ((row>>1)&3) (both-sides involution via pre-XOR'd global src).
// Per K-tile: R0 {rdA(cur,half0)+rdB(all); stage A(cur^1,kt+1); MFMA} bar;
// R1 {rdA(cur,half1); stage B(cur,kt+2) both halves; MFMA; vmcnt(2)} bar.
// Hazards: A(cur^1) last read kt-1 R1 (drained at kt-1 end barrier);
// B(cur) last read this-tile R0 (mid barrier). vmcnt(2) at tile end keeps
// only B(kt+2) in flight -> drains A(kt+1)+B(kt+1) exactly.
template <int NT, int LDA, int LDB, int BM, int BN, int THREADS, int MODE>
__global__ __launch_bounds__(THREADS, 4) void k_gemm(
    const ushort_t* __restrict__ A, const ushort_t* __restrict__ Bt,
    const float* __restrict__ probs, const float* __restrict__ b1,
    ushort_t* __restrict__ hp, float* __restrict__ out, int ntn) {
  constexpr int NWAVE = THREADS / 64;
  constexpr int WN = (BN == 256) ? 4 : 2;
  constexpr int WM = NWAVE / WN;
  constexpr int HA = BM / 2;                 // A half rows
  constexpr int FH = HA / (WM * 16);         // 2
  constexpr int BHR = BN / 2;
  constexpr int ATILE = BM * 64;             // bytes per A buf
  constexpr int BBYTES = BHR * 64;           // bytes per B half
  constexpr int BOFF = 2 * ATILE;
  constexpr int AR = (BM * 64) / (THREADS * 16);  // gloads per A stage

  extern __shared__ char lds[];
  const int tid = threadIdx.x;
  int bid = blockIdx.x;
  const int nwg = gridDim.x;                  // divisible by 8
  bid = (bid & 7) * (nwg >> 3) + (bid >> 3);  // XCD swizzle (bijective)
  const int bm = bid / ntn, bn = bid % ntn;

  const int wid = tid >> 6, lane = tid & 63;
  const int widM = wid / WN, widN = wid % WN;
  const int wmBase = widM * (FH * 16);
  const int wn = widN * 64;
  const int lr = lane & 15, g = lane >> 4;
  const int swz = (g ^ ((lr >> 1) & 3)) << 4;

  const ushort_t* Ag = A + (size_t)bm * BM * LDA;
  const ushort_t* Bg = Bt + (size_t)bn * BN * LDB;

  auto stageA = [&](int buf, int kt) {
#pragma unroll
    for (int r = 0; r < AR; ++r) {
      int srow = (tid >> 2) + r * (THREADS / 4);
      int scol = (((tid & 3) ^ ((srow >> 1) & 3)) << 4);
      gload16((const char*)(Ag + (size_t)srow * LDA) + kt * 64 + scol,
              lds + buf * ATILE + r * (THREADS * 16) + tid * 16);
    }
  };
  auto stageB = [&](int buf, int half, int kt) {
    int srow = tid >> 2;
    int scol = (((tid & 3) ^ ((srow >> 1) & 3)) << 4);
    gload16((const char*)(Bg + (size_t)(half * BHR + srow) * LDB) + kt * 64 + scol,
            lds + BOFF + (buf * 2 + half) * BBYTES + tid * 16);
  };
  auto rdA = [&](int buf, int half, int i) -> bf16x8 {
    int row = half * HA + wmBase + i * 16 + lr;
    return *(const bf16x8*)(lds + buf * ATILE + row * 64 + swz);
  };
  auto rdB = [&](int buf, int j) -> bf16x8 {
    int nr = wn + j * 16;
    int half = (nr >= BHR) ? 1 : 0;
    int r = (nr & (BHR - 1)) + lr;
    return *(const bf16x8*)(lds + BOFF + (buf * 2 + half) * BBYTES + r * 64 + swz);
  };

  f32x4 acc[2 * FH][4];
#pragma unroll
  for (int i = 0; i < 2 * FH; ++i)
#pragma unroll
    for (int j = 0; j < 4; ++j) acc[i][j] = (f32x4){0.f, 0.f, 0.f, 0.f};

  // prologue: tile0 {A,B0,B1} (oldest), then B(1) both halves.
  stageA(0, 0); stageB(0, 0, 0); stageB(0, 1, 0);
  stageB(1, 0, 1); stageB(1, 1, 1);
  asm volatile("s_waitcnt vmcnt(2)" ::: "memory");
  __builtin_amdgcn_sched_barrier(0);
  __builtin_amdgcn_s_barrier();
  __builtin_amdgcn_sched_barrier(0);

  auto body = [&](auto CURC, int kt) {
    constexpr int cur = decltype(CURC)::value;
    bf16x8 bfr[4];
    // ---------------- region 0 (A half 0, all B) ----------------
    {
      bf16x8 a0[FH];
#pragma unroll
      for (int i = 0; i < FH; ++i) a0[i] = rdA(cur, 0, i);
#pragma unroll
      for (int j = 0; j < 4; ++j) bfr[j] = rdB(cur, j);
      if (kt + 1 < NT) stageA(cur ^ 1, kt + 1);
      __builtin_amdgcn_s_setprio(1);
#pragma unroll
      for (int j = 0; j < 4; ++j)
#pragma unroll
        for (int i = 0; i < FH; ++i)
          acc[i][j] = __builtin_amdgcn_mfma_f32_16x16x32_bf16(
              a0[i], bfr[j], acc[i][j], 0, 0, 0);
      __builtin_amdgcn_s_setprio(0);
    }
    __builtin_amdgcn_s_barrier();
    __builtin_amdgcn_sched_barrier(0);
    // ---------------- region 1 (A half 1, reuse bfr) ----------------
    {
      bf16x8 a1[FH];
#pragma unroll
      for (int i = 0; i < FH; ++i) a1[i] = rdA(cur, 1, i);
      if (kt + 2 < NT) { stageB(cur, 0, kt + 2); stageB(cur, 1, kt + 2); }
      __builtin_amdgcn_s_setprio(1);
#pragma unroll
      for (int j = 0; j < 4; ++j)
#pragma unroll
        for (int i = 0; i < FH; ++i)
          acc[FH + i][j] = __builtin_amdgcn_mfma_f32_16x16x32_bf16(
              a1[i], bfr[j], acc[FH + i][j], 0, 0, 0);
      __builtin_amdgcn_s_setprio(0);
    }
    if (kt + 2 < NT) {
      asm volatile("s_waitcnt vmcnt(2)" ::: "memory");
      __builtin_amdgcn_sched_barrier(0);
    } else if (kt + 1 < NT) {
      asm volatile("s_waitcnt vmcnt(0)" ::: "memory");
      __builtin_amdgcn_sched_barrier(0);
    }
    __builtin_amdgcn_s_barrier();
    __builtin_amdgcn_sched_barrier(0);
  };

  int kt = 0;
#pragma unroll 1
  for (int it = 0; it < NT / 2; ++it) {
    body(ic<0>{}, kt); ++kt;
    body(ic<1>{}, kt); ++kt;
  }

  // epilogue: C/D layout col=lane&15, row=(lane>>4)*4+reg
  const int rowb = bm * BM + wmBase + g * 4;
  const int colb = bn * BN + wn + lr;
  if (MODE == 0) {
    const int leaf = bn;   // BN=256 tile == one leaf
#pragma unroll
    for (int q = 0; q < 2; ++q)
#pragma unroll
      for (int i = 0; i < FH; ++i) {
        int rbase = rowb + q * HA + i * 16;
        float pm[4];
#pragma unroll
        for (int rg = 0; rg < 4; ++rg)
          pm[rg] = probs[(size_t)(rbase + rg) * 16 + leaf];
#pragma unroll
        for (int j = 0; j < 4; ++j) {
          float bias = b1[colb + j * 16];
#pragma unroll
          for (int rg = 0; rg < 4; ++rg) {
            float v = acc[q * FH + i][j][rg] + bias;
            v = v > 0.f ? v : 0.f;
            v *= pm[rg];
            hp[(size_t)(rbase + rg) * K2 + colb + j * 16] = f2bf(v);
          }
        }
      }
  } else {
#pragma unroll
    for (int q = 0; q < 2; ++q)
#pragma unroll
      for (int i = 0; i < FH; ++i) {
        int rbase = rowb + q * HA + i * 16;
#pragma unroll
        for (int j = 0; j < 4; ++j)
#pragma unroll
          for (int rg = 0; rg < 4; ++rg)
            out[(size_t)(rbase + rg) * N2 + colb + j * 16] = acc[q * FH + i][j][rg];
      }
  }
}

extern "C" void kernel_launch(void* const* d_in, const int* in_sizes, int n_in,
                              void* d_out, int out_size, void* d_ws, size_t ws_size,
                              hipStream_t stream) {
  const float* x      = (const float*)d_in[0];
  const float* node_w = (const float*)d_in[1];
  const float* node_b = (const float*)d_in[2];
  const float* w1     = (const float*)d_in[3];
  const float* b1     = (const float*)d_in[4];
  const float* w2     = (const float*)d_in[5];
  const float* b2     = (const float*)d_in[6];
  float* out = (float*)d_out;

  char* ws = (char*)d_ws;
  ushort_t* xb    = (ushort_t*)(ws);
  ushort_t* w1t   = (ushort_t*)(ws + 16777216);
  ushort_t* w2t   = (ushort_t*)(ws + 25165824);
  ushort_t* hp    = (ushort_t*)(ws + 33685504);
  float*    probs = (float*)   (ws + 101842944);

  k_prep<<<4352, 256, 0, stream>>>(x, node_w, node_b, w1, w2, b2,
                                   xb, probs, w1t, w2t, hp);
  // GEMM1: 8192x4096 K=1024: BM=128 BN=256 BK=32, 64x16=1024 blocks,
  // LDS 48 KiB -> 2 blocks/CU
  k_gemm<32, K1, K1, 128, 256, 512, 0><<<1024, 512, 49152, stream>>>(
      xb, w1t, probs, b1, hp, nullptr, N1 / 256);
  // GEMM2: 8192x1024 K=4160: BM=128 BN=128 BK=32, 64x8=512 blocks,
  // LDS 32 KiB -> 2 blocks/CU
  k_gemm<130, K2, K2, 128, 128, 256, 1><<<512, 256, 32768, stream>>>(
      hp, w2t, nullptr, nullptr, nullptr, out, N2 / 128);
}

// Round 8
// 182.818 us; speedup vs baseline: 1.0312x; 1.0312x over previous
//
#include <hip/hip_runtime.h>
#include <stdint.h>

typedef unsigned short ushort_t;
typedef __bf16 bf16x8 __attribute__((ext_vector_type(8)));
typedef float f32x4 __attribute__((ext_vector_type(4)));

#define M_TOK 8192
#define K1 1024
#define N1 4096
#define K2 4160   /* 4096 (h) + 16 (probs/b2) + 48 zero-pad */
#define N2 1024

template <int V> struct ic { static constexpr int value = V; };

__device__ __forceinline__ ushort_t f2bf(float f) {
  union { float f; unsigned u; } v; v.f = f;
  unsigned u = v.u;
  u += 0x7FFFu + ((u >> 16) & 1u);   // RNE; inputs finite
  return (ushort_t)(u >> 16);
}

__device__ __forceinline__ void gload16(const void* g, void* l) {
  __builtin_amdgcn_global_load_lds((__attribute__((address_space(1))) void*)g,
                                   (__attribute__((address_space(3))) void*)l,
                                   16, 0, 0);
}

// ---------------- merged prep: wprep (blocks 0..2303) + probs (2304..4351) --
__global__ __launch_bounds__(256) void k_prep(
    const float* __restrict__ x, const float* __restrict__ node_w,
    const float* __restrict__ node_b, const float* __restrict__ w1,
    const float* __restrict__ w2, const float* __restrict__ b2,
    ushort_t* __restrict__ xb, float* __restrict__ probs,
    ushort_t* __restrict__ w1t, ushort_t* __restrict__ w2t,
    ushort_t* __restrict__ hp) {
  __shared__ ushort_t tile[64][68];
  const int b = blockIdx.x;
  if (b < 1024) {
    // w1t[l*256+h][k] = w1[l][k][h]
    const int tr = threadIdx.x >> 4, tc = (threadIdx.x & 15) * 4;
    const int l = b >> 6, rem = b & 63;
    const int kt = rem >> 2, ht = rem & 3;
    const float* in = w1 + (size_t)l * K1 * 256;
#pragma unroll
    for (int rr = 0; rr < 4; ++rr) {
      int r = tr + rr * 16;
      float4 v = *(const float4*)(in + (size_t)(kt * 64 + r) * 256 + ht * 64 + tc);
      tile[r][tc+0] = f2bf(v.x); tile[r][tc+1] = f2bf(v.y);
      tile[r][tc+2] = f2bf(v.z); tile[r][tc+3] = f2bf(v.w);
    }
    __syncthreads();
#pragma unroll
    for (int rr = 0; rr < 4; ++rr) {
      int oh = tr + rr * 16;
      ushort4 o;
      o.x = tile[tc+0][oh]; o.y = tile[tc+1][oh];
      o.z = tile[tc+2][oh]; o.w = tile[tc+3][oh];
      *(ushort4*)(w1t + (size_t)(l * 256 + ht * 64 + oh) * K1 + kt * 64 + tc) = o;
    }
  } else if (b < 2048) {
    // w2t[d][l*256+h] = w2[l][h][d]
    const int tr = threadIdx.x >> 4, tc = (threadIdx.x & 15) * 4;
    const int bb = b - 1024;
    const int l = bb >> 6, rem = bb & 63;
    const int ht = rem >> 4, dt = rem & 15;
    const float* in = w2 + (size_t)l * 256 * N2;
#pragma unroll
    for (int rr = 0; rr < 4; ++rr) {
      int r = tr + rr * 16;
      float4 v = *(const float4*)(in + (size_t)(ht * 64 + r) * N2 + dt * 64 + tc);
      tile[r][tc+0] = f2bf(v.x); tile[r][tc+1] = f2bf(v.y);
      tile[r][tc+2] = f2bf(v.z); tile[r][tc+3] = f2bf(v.w);
    }
    __syncthreads();
#pragma unroll
    for (int rr = 0; rr < 4; ++rr) {
      int od = tr + rr * 16;
      ushort4 o;
      o.x = tile[tc+0][od]; o.y = tile[tc+1][od];
      o.z = tile[tc+2][od]; o.w = tile[tc+3][od];
      *(ushort4*)(w2t + (size_t)(dt * 64 + od) * K2 + l * 256 + ht * 64 + tc) = o;
    }
  } else if (b < 2304) {
    int tid = (b - 2048) * 256 + threadIdx.x;   // 1024 * 64
    int d = tid >> 6, cc = tid & 63;
    float v = (cc < 16) ? b2[cc * N2 + d] : 0.f;
    w2t[(size_t)d * K2 + 4096 + cc] = f2bf(v);
  } else {
    // probs + x->bf16; 1 wave per token
    const int wid = threadIdx.x >> 6, lane = threadIdx.x & 63;
    const int t = (b - 2304) * 4 + wid;
    const float* xr = x + (size_t)t * K1;
    float xv[16];
#pragma unroll
    for (int j = 0; j < 4; ++j) {
      float4 v = *(const float4*)(xr + j * 256 + lane * 4);
      xv[4*j+0] = v.x; xv[4*j+1] = v.y; xv[4*j+2] = v.z; xv[4*j+3] = v.w;
    }
    ushort_t* xbr = xb + (size_t)t * K1;
#pragma unroll
    for (int j = 0; j < 4; ++j) {
      ushort4 o;
      o.x = f2bf(xv[4*j+0]); o.y = f2bf(xv[4*j+1]);
      o.z = f2bf(xv[4*j+2]); o.w = f2bf(xv[4*j+3]);
      *(ushort4*)(xbr + j * 256 + lane * 4) = o;
    }
    float c[15];
#pragma unroll
    for (int n = 0; n < 15; ++n) {
      float s = 0.f;
      const float* wr = node_w + n * K1;
#pragma unroll
      for (int j = 0; j < 4; ++j) {
        float4 w = *(const float4*)(wr + j * 256 + lane * 4);
        s += xv[4*j+0]*w.x + xv[4*j+1]*w.y + xv[4*j+2]*w.z + xv[4*j+3]*w.w;
      }
#pragma unroll
      for (int off = 32; off > 0; off >>= 1) s += __shfl_xor(s, off);
      float z = s + node_b[n];
      c[n] = 1.f / (1.f + __expf(-z));
    }
    if (lane < 16) {
      float p = 1.f;
#pragma unroll
      for (int m = 0; m < 4; ++m) {
        int jm = lane >> (4 - m);
        int node = (1 << m) - 1 + jm;
        int bit = (lane >> (3 - m)) & 1;
        p *= bit ? (1.f - c[node]) : c[node];
      }
      probs[t * 16 + lane] = p;
      hp[(size_t)t * K2 + 4096 + lane] = f2bf(p);
    }
    if (lane < 48) hp[(size_t)t * K2 + 4112 + lane] = 0;
  }
}

// ---- 256x128 MFMA GEMM, ring-3 LDS, 1 barrier/K-tile, reg-pipelined reads --
// Per tile kt (2 chunks of 16 MFMA):
//  c0: read A m2,m3 (for c1's MFMA) | stage half0(kt+2) | SB0 | MFMA m0,m1
//      (operands a01[P], bfr[P] read during previous chunk)
//  c1: vmcnt(3); s_barrier; read tile-(kt+1) A m0,m1 + B -> sets [P^1] |
//      stage half1(kt+2) | SB0 | MFMA m2,m3 (a23, bfr[P])
// Reads are never consumed by the MFMAs they precede -> LDS pipe drains
// under the MFMA burst. Ring-3: tile kt+1 fully resident at barrier B_kt
// (staged during kt-1, drained by vmcnt chain). Stage target (kt+2)%3 =
// (kt-1)%3, last read in c0(kt-1), separated by B_(kt-1). vmcnt(3) keeps
// exactly the newest stage-half (verified by issue-order bookkeeping).
template <int NT, int LDA, int LDB, int MODE>
__global__ __launch_bounds__(512, 2) void k_gemm3(
    const ushort_t* __restrict__ A, const ushort_t* __restrict__ Bt,
    const float* __restrict__ probs, const float* __restrict__ b1,
    ushort_t* __restrict__ hp, float* __restrict__ out, int ntn) {
  constexpr int ATILE = 256 * 128;            // 32 KB
  constexpr int BTILE = 128 * 128;            // 16 KB
  constexpr int TBYTES = ATILE + BTILE;       // 48 KB
  extern __shared__ char lds[];
  const int tid = threadIdx.x;
  int bid = blockIdx.x;
  const int nwg = gridDim.x;                  // divisible by 8
  bid = (bid & 7) * (nwg >> 3) + (bid >> 3);  // XCD swizzle (bijective)
  const int bm = bid / ntn, bn = bid % ntn;

  const int wid = tid >> 6, lane = tid & 63;
  const int widM = wid >> 1, widN = wid & 1;  // 4M x 2N
  const int lr = lane & 15, g = lane >> 4;

  const ushort_t* Ag = A + (size_t)bm * 256 * LDA;
  const ushort_t* Bg = Bt + (size_t)bn * 128 * LDB;

  // staging: slot s -> row=s>>3, 16B-slot=s&7; swizzle col16 ^= row&7
  auto stageHalf = [&](char* base, int kt, int part) {
#pragma unroll
    for (int r = 0; r < 2; ++r) {
      int s = tid + part * 1024 + r * 512;
      int row = s >> 3;
      int c16 = (s & 7) ^ (row & 7);
      gload16((const char*)(Ag + (size_t)row * LDA) + kt * 128 + (c16 << 4),
              base + s * 16);
    }
    {
      int s = tid + part * 512;
      int row = s >> 3;
      int c16 = (s & 7) ^ (row & 7);
      gload16((const char*)(Bg + (size_t)row * LDB) + kt * 128 + (c16 << 4),
              base + ATILE + s * 16);
    }
  };
  auto rdA = [&](char* base, int mi, int kk) -> bf16x8 {
    int row = widM * 64 + mi * 16 + lr;
    return *(const bf16x8*)(base + row * 128 + (((kk * 4 + g) ^ (lr & 7)) << 4));
  };
  auto rdB = [&](char* base, int nj, int kk) -> bf16x8 {
    int row = widN * 64 + nj * 16 + lr;
    return *(const bf16x8*)(base + ATILE + row * 128 + (((kk * 4 + g) ^ (lr & 7)) << 4));
  };

  f32x4 acc[4][4];
#pragma unroll
  for (int i = 0; i < 4; ++i)
#pragma unroll
    for (int j = 0; j < 4; ++j) acc[i][j] = (f32x4){0.f, 0.f, 0.f, 0.f};

  bf16x8 a01[2][4];   // [parity][mi*2+kk], mi in {0,1}
  bf16x8 bfr[2][8];   // [parity][nj*2+kk]
  bf16x8 a23[4];      // [(mi-2)*2+kk], single-buffered (read c0, used c1)

  char* r0 = lds;
  char* r1 = lds + TBYTES;
  char* r2 = lds + 2 * TBYTES;

  // prologue: tiles 0,1 staged fully (issue order t0 then t1)
  stageHalf(r0, 0, 0); stageHalf(r0, 0, 1);
  stageHalf(r1, 1, 0); stageHalf(r1, 1, 1);
  asm volatile("s_waitcnt vmcnt(6)" ::: "memory");   // t0 resident
  __builtin_amdgcn_sched_barrier(0);
  __builtin_amdgcn_s_barrier();
  __builtin_amdgcn_sched_barrier(0);
  // pre-read c0(0) operands (parity 0) -- the only dependent reads
#pragma unroll
  for (int mi = 0; mi < 2; ++mi)
#pragma unroll
    for (int kk = 0; kk < 2; ++kk) a01[0][mi * 2 + kk] = rdA(r0, mi, kk);
#pragma unroll
  for (int nj = 0; nj < 4; ++nj)
#pragma unroll
    for (int kk = 0; kk < 2; ++kk) bfr[0][nj * 2 + kk] = rdB(r0, nj, kk);

  auto body = [&](auto PARC, int kt, char* cur, char* nxt, char* stg) {
    constexpr int P = decltype(PARC)::value;
    // ---- chunk 0 ----
#pragma unroll
    for (int mi = 0; mi < 2; ++mi)
#pragma unroll
      for (int kk = 0; kk < 2; ++kk) a23[mi * 2 + kk] = rdA(cur, mi + 2, kk);
    if (kt + 2 < NT) stageHalf(stg, kt + 2, 0);
    __builtin_amdgcn_sched_barrier(0);
    __builtin_amdgcn_s_setprio(1);
#pragma unroll
    for (int kk = 0; kk < 2; ++kk)
#pragma unroll
      for (int nj = 0; nj < 4; ++nj)
#pragma unroll
        for (int mi = 0; mi < 2; ++mi)
          acc[mi][nj] = __builtin_amdgcn_mfma_f32_16x16x32_bf16(
              a01[P][mi * 2 + kk], bfr[P][nj * 2 + kk], acc[mi][nj], 0, 0, 0);
    __builtin_amdgcn_s_setprio(0);
    // ---- chunk 1 ----
    if (kt + 1 < NT) {
      if (kt + 2 < NT) asm volatile("s_waitcnt vmcnt(3)" ::: "memory");
      else             asm volatile("s_waitcnt vmcnt(0)" ::: "memory");
      __builtin_amdgcn_sched_barrier(0);
      __builtin_amdgcn_s_barrier();
      __builtin_amdgcn_sched_barrier(0);
#pragma unroll
      for (int mi = 0; mi < 2; ++mi)
#pragma unroll
        for (int kk = 0; kk < 2; ++kk) a01[P ^ 1][mi * 2 + kk] = rdA(nxt, mi, kk);
#pragma unroll
      for (int nj = 0; nj < 4; ++nj)
#pragma unroll
        for (int kk = 0; kk < 2; ++kk) bfr[P ^ 1][nj * 2 + kk] = rdB(nxt, nj, kk);
      if (kt + 2 < NT) stageHalf(stg, kt + 2, 1);
    }
    __builtin_amdgcn_sched_barrier(0);
    __builtin_amdgcn_s_setprio(1);
#pragma unroll
    for (int kk = 0; kk < 2; ++kk)
#pragma unroll
      for (int nj = 0; nj < 4; ++nj)
#pragma unroll
        for (int mi = 0; mi < 2; ++mi)
          acc[2 + mi][nj] = __builtin_amdgcn_mfma_f32_16x16x32_bf16(
              a23[mi * 2 + kk], bfr[P][nj * 2 + kk], acc[2 + mi][nj], 0, 0, 0);
    __builtin_amdgcn_s_setprio(0);
  };

  int kt = 0;
#pragma unroll 1
  for (int it = 0; it < NT / 2; ++it) {
    body(ic<0>{}, kt, r0, r1, r2); ++kt;
    { char* t = r0; r0 = r1; r1 = r2; r2 = t; }
    body(ic<1>{}, kt, r0, r1, r2); ++kt;
    { char* t = r0; r0 = r1; r1 = r2; r2 = t; }
  }
  if constexpr (NT & 1) body(ic<0>{}, kt, r0, r1, r2);

  // epilogue: C/D layout col=lane&15, row=(lane>>4)*4+reg
  const int rowb = bm * 256 + widM * 64 + g * 4;
  const int colb = bn * 128 + widN * 64 + lr;
  if (MODE == 0) {
    const int leaf = bn >> 1;   // 128-wide tile lies within one 256-wide leaf
#pragma unroll
    for (int mi = 0; mi < 4; ++mi) {
      int rbase = rowb + mi * 16;
      float pm[4];
#pragma unroll
      for (int rg = 0; rg < 4; ++rg)
        pm[rg] = probs[(size_t)(rbase + rg) * 16 + leaf];
#pragma unroll
      for (int nj = 0; nj < 4; ++nj) {
        float bias = b1[colb + nj * 16];
#pragma unroll
        for (int rg = 0; rg < 4; ++rg) {
          float v = acc[mi][nj][rg] + bias;
          v = v > 0.f ? v : 0.f;
          v *= pm[rg];
          hp[(size_t)(rbase + rg) * K2 + colb + nj * 16] = f2bf(v);
        }
      }
    }
  } else {
#pragma unroll
    for (int mi = 0; mi < 4; ++mi) {
      int rbase = rowb + mi * 16;
#pragma unroll
      for (int nj = 0; nj < 4; ++nj)
#pragma unroll
        for (int rg = 0; rg < 4; ++rg)
          out[(size_t)(rbase + rg) * N2 + colb + nj * 16] = acc[mi][nj][rg];
    }
  }
}

extern "C" void kernel_launch(void* const* d_in, const int* in_sizes, int n_in,
                              void* d_out, int out_size, void* d_ws, size_t ws_size,
                              hipStream_t stream) {
  const float* x      = (const float*)d_in[0];
  const float* node_w = (const float*)d_in[1];
  const float* node_b = (const float*)d_in[2];
  const float* w1     = (const float*)d_in[3];
  const float* b1     = (const float*)d_in[4];
  const float* w2     = (const float*)d_in[5];
  const float* b2     = (const float*)d_in[6];
  float* out = (float*)d_out;

  char* ws = (char*)d_ws;
  ushort_t* xb    = (ushort_t*)(ws);
  ushort_t* w1t   = (ushort_t*)(ws + 16777216);
  ushort_t* w2t   = (ushort_t*)(ws + 25165824);
  ushort_t* hp    = (ushort_t*)(ws + 33685504);
  float*    probs = (float*)   (ws + 101842944);

  k_prep<<<4352, 256, 0, stream>>>(x, node_w, node_b, w1, w2, b2,
                                   xb, probs, w1t, w2t, hp);
  // GEMM1: 8192x4096 K=1024: BM=256 BN=128 BK=64, 32x32=1024 blocks,
  // ring-3 LDS 144 KiB
  k_gemm3<16, K1, K1, 0><<<1024, 512, 147456, stream>>>(
      xb, w1t, probs, b1, hp, nullptr, N1 / 128);
  // GEMM2: 8192x1024 K=4160: 32x8=256 blocks
  k_gemm3<65, K2, K2, 1><<<256, 512, 147456, stream>>>(
      hp, w2t, nullptr, nullptr, nullptr, out, N2 / 128);
}